// Round 5
// baseline (83.830 us; speedup 1.0000x reference)
//
#include <hip/hip_runtime.h>
#include <float.h>

// x: [B=32][C=3][L=8192] f32, weight: [O=128][C=3][K=64] f32
// out[b][o] = -2 * max_t ( conv(b,o,t) - ||w_o||^2/2 - ||win_{b,t}||^2/2 ), t in [0, 8129)
#define BB 32
#define LL 8192
#define OO 128
#define KK 64
#define WW (LL - KK + 1)   // 8129
#define TC 32              // t-chunks of 256

typedef __attribute__((ext_vector_type(8))) short short8;
typedef __attribute__((ext_vector_type(4))) float f32x4;

union AB { int4 i4; int i[4]; short8 v; };

static __device__ __forceinline__ unsigned int f2bf(float f) {
    unsigned int u = __builtin_bit_cast(unsigned int, f);
    return (u + 0x7FFFu + ((u >> 16) & 1u)) >> 16;   // RNE
}

// ---- prep: W -> bf16 swizzled into A-fragment order; wn[o] = ||w_o||^2/2 (fp32) ----
// wswz 16B-chunk index g (per ob half of 1536): ((ks*4+qp)*64 + o_local), chunk holds
// w[o][c*64 + h*32 + qp*8 .. +8) as bf16, with ks = 2c+h. Main stages this half with
// 6 coalesced int4 loads/thread -> LDS is already in fragment-read order.
__global__ __launch_bounds__(256) void prep_kernel(const float* __restrict__ w,
                                                   unsigned short* __restrict__ wswz,
                                                   float* __restrict__ wn) {
    int g = blockIdx.x * 256 + threadIdx.x;
    if (g < 3072) {
        int ob = (g >= 1536) ? 1 : 0;
        int gg = g - ob * 1536;
        int ksqp = gg >> 6;          // 0..23
        int o2   = gg & 63;
        int ks = ksqp >> 2, qp = ksqp & 3;
        int c = ks >> 1, h = ks & 1;
        const float4* p = (const float4*)(w + (ob * 64 + o2) * 192 + c * 64 + h * 32 + qp * 8);
        float4 v0 = p[0], v1 = p[1];
        int4 pk;
        pk.x = (int)(f2bf(v0.x) | (f2bf(v0.y) << 16));
        pk.y = (int)(f2bf(v0.z) | (f2bf(v0.w) << 16));
        pk.z = (int)(f2bf(v1.x) | (f2bf(v1.y) << 16));
        pk.w = (int)(f2bf(v1.z) | (f2bf(v1.w) << 16));
        ((int4*)wswz)[g] = pk;
    }
    int oo = g - 3072;
    if (oo >= 0 && oo < OO) {
        const float* p = w + oo * 192;
        float s = 0.f;
        for (int i = 0; i < 192; ++i) { float v = p[i]; s = fmaf(v, v, s); }
        wn[oo] = 0.5f * s;
    }
}

// ---- main: grid (32 tc, 2 ob, 32 b) = 2048 blocks, 4 waves ----
// Wave (wo=wv&1, wt=wv>>1): o in [64ob+32wo, +32), t = 256tc + 128wt + r + 8n.
__global__ __launch_bounds__(256, 4) void shapeconv_main(const float* __restrict__ x,
                                                         const unsigned short* __restrict__ wswz,
                                                         const float* __restrict__ wn,
                                                         float* __restrict__ partial) {
    __shared__ __align__(16) unsigned short w_lds[64 * 192];   // 24576 B, swizzled
    __shared__ __align__(16) unsigned short x_lds[3 * 320];
    __shared__ float sq_lds[320];
    __shared__ float P_lds[40];
    __shared__ float win_lds[272];     // padded idx t + (t>>4)
    __shared__ float wn_lds[64];
    __shared__ float mred[64];

    const int tc = blockIdx.x;
    const int ob = blockIdx.y;
    const int b  = blockIdx.z;
    const int tid = threadIdx.x;
    const int wv = tid >> 6;
    const int lane = tid & 63;
    const int wo = wv & 1, wt = wv >> 1;
    const int n  = lane & 15;
    const int qp = lane >> 4;
    const int T0 = tc * 256;

    // W stage: 6 coalesced 16B copies per thread (1 cache line per wave-instr)
    {
        const int4* src = (const int4*)wswz + ob * 1536;
        int4* dst = (int4*)w_lds;
        #pragma unroll
        for (int i = 0; i < 6; ++i)
            dst[tid + 256 * i] = src[tid + 256 * i];
    }
    if (tid < 64) wn_lds[tid] = wn[ob * 64 + tid];

    // x tile -> bf16 LDS (coalesced float4)
    if (tid < 240) {
        int c = tid / 80, j4 = tid - c * 80;
        int l = T0 + j4 * 4;
        float4 v = make_float4(0.f, 0.f, 0.f, 0.f);
        if (l < LL) v = *(const float4*)(x + (b * 3 + c) * LL + l);
        uint2 pk;
        pk.x = f2bf(v.x) | (f2bf(v.y) << 16);
        pk.y = f2bf(v.z) | (f2bf(v.w) << 16);
        *(uint2*)(x_lds + c * 320 + j4 * 4) = pk;
    }
    // sq[j] fp32 (L1-hot re-read of same lines)
    for (int j = tid; j < 320; j += 256) {
        int l = T0 + j;
        float s = 0.f;
        if (l < LL) {
            #pragma unroll
            for (int c = 0; c < 3; ++c) {
                float v = x[(b * 3 + c) * LL + l];
                s = fmaf(v, v, s);
            }
        }
        sq_lds[j] = s;
    }
    // P8 partials
    if (tid < 40) {
        float s = 0.f;
        #pragma unroll
        for (int k = 0; k < 8; ++k) {
            int l = T0 + tid * 8 + k;
            if (l < LL) {
                #pragma unroll
                for (int c = 0; c < 3; ++c) {
                    float v = x[(b * 3 + c) * LL + l];
                    s = fmaf(v, v, s);
                }
            }
        }
        P_lds[tid] = s;
    }
    __syncthreads();   // B1

    // win[t] = 0.5 * sum_{k<64} sq[t+k]; invalid t -> +1e30
    {
        int a = tid >> 3, bb2 = tid & 7;
        float s = 0.f;
        #pragma unroll
        for (int i = 1; i <= 7; ++i) s += P_lds[a + i];
        #pragma unroll
        for (int k = 0; k < 8; ++k)
            s += (k >= bb2) ? sq_lds[8 * a + k] : sq_lds[8 * a + 64 + k];
        int pi = tid + (tid >> 4);
        win_lds[pi] = (T0 + tid < WW) ? 0.5f * s : 1e30f;
    }
    __syncthreads();   // B2

    // acc init with -(wn + win)
    f32x4 acc[2][8];
    {
        float wl[8];
        #pragma unroll
        for (int r = 0; r < 8; ++r) {
            int tl = 128 * wt + r + 8 * n;
            wl[r] = win_lds[tl + (tl >> 4)];
        }
        #pragma unroll
        for (int ot = 0; ot < 2; ++ot)
            #pragma unroll
            for (int rg = 0; rg < 4; ++rg) {
                float nw = wn_lds[32 * wo + 16 * ot + 4 * qp + rg];
                #pragma unroll
                for (int r = 0; r < 8; ++r)
                    acc[ot][r][rg] = -nw - wl[r];
            }
    }

    // K-loop: 6 ks x 8 r x 2 ot = 96 MFMAs/wave
    const char* xb = (const char*)x_lds;
    #pragma unroll
    for (int ks = 0; ks < 6; ++ks) {
        int c = ks >> 1, h = ks & 1;
        int e0b = c * 640 + 256 * wt + 64 * h + 16 * (n + qp);
        int4 Ea = *(const int4*)(xb + e0b);
        int4 Eb = *(const int4*)(xb + e0b + 16);
        int D[8] = {Ea.x, Ea.y, Ea.z, Ea.w, Eb.x, Eb.y, Eb.z, Eb.w};
        AB a0, a1;
        const int4* wq = (const int4*)w_lds + (ks * 4 + qp) * 64 + 32 * wo;
        a0.i4 = wq[n];
        a1.i4 = wq[16 + n];
        #pragma unroll
        for (int r = 0; r < 8; ++r) {
            AB bf;
            int s = r >> 1;
            if ((r & 1) == 0) {
                bf.i[0] = D[s]; bf.i[1] = D[s + 1]; bf.i[2] = D[s + 2]; bf.i[3] = D[s + 3];
            } else {
                #pragma unroll
                for (int d = 0; d < 4; ++d)
                    bf.i[d] = (int)(((unsigned)D[s + d] >> 16) | ((unsigned)D[s + d + 1] << 16));
            }
            acc[0][r] = __builtin_amdgcn_mfma_f32_16x16x32_bf16(a0.v, bf.v, acc[0][r], 0, 0, 0);
            acc[1][r] = __builtin_amdgcn_mfma_f32_16x16x32_bf16(a1.v, bf.v, acc[1][r], 0, 0, 0);
        }
    }

    // epilogue: register max -> cross-lane over n -> wt-pair combine -> dump
    float m2[2][4];
    #pragma unroll
    for (int ot = 0; ot < 2; ++ot)
        #pragma unroll
        for (int rg = 0; rg < 4; ++rg) {
            float mm = acc[ot][0][rg];
            #pragma unroll
            for (int r = 1; r < 8; ++r) mm = fmaxf(mm, acc[ot][r][rg]);
            m2[ot][rg] = mm;
        }
    #pragma unroll
    for (int s = 1; s <= 8; s <<= 1)
        #pragma unroll
        for (int ot = 0; ot < 2; ++ot)
            #pragma unroll
            for (int rg = 0; rg < 4; ++rg)
                m2[ot][rg] = fmaxf(m2[ot][rg], __shfl_xor(m2[ot][rg], s, 64));

    if (wt == 1 && n == 0) {
        #pragma unroll
        for (int ot = 0; ot < 2; ++ot)
            #pragma unroll
            for (int rg = 0; rg < 4; ++rg)
                mred[32 * wo + 16 * ot + 4 * qp + rg] = m2[ot][rg];
    }
    __syncthreads();   // B3
    if (wt == 0 && n == 0) {
        #pragma unroll
        for (int ot = 0; ot < 2; ++ot)
            #pragma unroll
            for (int rg = 0; rg < 4; ++rg) {
                int oi = 32 * wo + 16 * ot + 4 * qp + rg;
                float v = fmaxf(m2[ot][rg], mred[oi]);
                partial[((size_t)(b * TC + tc) * 2 + ob) * 64 + oi] = v;
            }
    }
}

// max over the 32 t-chunks, scale by -2
__global__ __launch_bounds__(256) void reduce_kernel(const float* __restrict__ partial,
                                                     float* __restrict__ out) {
    int idx = blockIdx.x * 256 + threadIdx.x;   // 4096 = 32*128
    int b = idx >> 7, o = idx & 127;
    const float* pp = partial + ((size_t)b * TC * 2 + (o >> 6)) * 64 + (o & 63);
    float mx = -FLT_MAX;
    #pragma unroll 8
    for (int tcc = 0; tcc < TC; ++tcc) mx = fmaxf(mx, pp[(size_t)tcc * 128]);
    out[idx] = -2.f * mx;
}

extern "C" void kernel_launch(void* const* d_in, const int* in_sizes, int n_in,
                              void* d_out, int out_size, void* d_ws, size_t ws_size,
                              hipStream_t stream) {
    const float* x = (const float*)d_in[0];   // [32][3][8192]
    const float* w = (const float*)d_in[1];   // [128][3][64]
    float* out = (float*)d_out;               // [32][128]

    // ws: wswz bf16 swizzled [3072 x 16B] (49152 B) | wn f32 [128] | partial f32 [32][32][2][64]
    unsigned short* wswz = (unsigned short*)d_ws;
    float* wn = (float*)((char*)d_ws + 49152);
    float* partial = (float*)((char*)d_ws + 49664);

    prep_kernel<<<13, 256, 0, stream>>>(w, wswz, wn);
    dim3 grid(TC, 2, BB);                     // 2048 blocks
    shapeconv_main<<<grid, 256, 0, stream>>>(x, wswz, wn, partial);
    reduce_kernel<<<16, 256, 0, stream>>>(partial, out);
}

// Round 6
// 82.636 us; speedup vs baseline: 1.0144x; 1.0144x over previous
//
#include <hip/hip_runtime.h>
#include <float.h>

// x: [B=32][C=3][L=8192] f32, weight: [O=128][C=3][K=64] f32
// out[b][o] = -2 * max_t ( conv(b,o,t) - ||w_o||^2/2 - ||win_{b,t}||^2/2 ), t in [0, 8129)
#define BB 32
#define LL 8192
#define OO 128
#define KK 64
#define WW (LL - KK + 1)   // 8129
#define TC 32              // t-chunks of 256

typedef __attribute__((ext_vector_type(8))) short short8;
typedef __attribute__((ext_vector_type(4))) float f32x4;

union AB { int4 i4; int i[4]; short8 v; };
union AB2 { struct { int4 a, b; } p; int i[8]; };

static __device__ __forceinline__ unsigned int f2bf(float f) {
    unsigned int u = __builtin_bit_cast(unsigned int, f);
    return (u + 0x7FFFu + ((u >> 16) & 1u)) >> 16;   // RNE
}

// ---- prep: W -> bf16 swizzled into A-fragment order; wn[o] = ||w_o||^2/2 (fp32) ----
// wswz 16B-chunk index (per ob half of 1536): ((ks*4+qp)*64 + o_local); chunk =
// w[o][c*64 + h*32 + qp*8 .. +8) bf16, ks = 2c+h.
__global__ __launch_bounds__(256) void prep_kernel(const float* __restrict__ w,
                                                   unsigned short* __restrict__ wswz,
                                                   float* __restrict__ wn) {
    int g = blockIdx.x * 256 + threadIdx.x;
    if (g < 3072) {
        int ob = (g >= 1536) ? 1 : 0;
        int gg = g - ob * 1536;
        int ksqp = gg >> 6;
        int o2   = gg & 63;
        int ks = ksqp >> 2, qp = ksqp & 3;
        int c = ks >> 1, h = ks & 1;
        const float4* p = (const float4*)(w + (ob * 64 + o2) * 192 + c * 64 + h * 32 + qp * 8);
        float4 v0 = p[0], v1 = p[1];
        int4 pk;
        pk.x = (int)(f2bf(v0.x) | (f2bf(v0.y) << 16));
        pk.y = (int)(f2bf(v0.z) | (f2bf(v0.w) << 16));
        pk.z = (int)(f2bf(v1.x) | (f2bf(v1.y) << 16));
        pk.w = (int)(f2bf(v1.z) | (f2bf(v1.w) << 16));
        ((int4*)wswz)[g] = pk;
    }
    int oo = g - 3072;
    if (oo >= 0 && oo < OO) {
        const float* p = w + oo * 192;
        float s = 0.f;
        for (int i = 0; i < 192; ++i) { float v = p[i]; s = fmaf(v, v, s); }
        wn[oo] = 0.5f * s;
    }
}

// ---- main: grid (32 tc, 2 ob, 32 b) = 2048 blocks, 4 waves ----
// Wave (wo=wv&1, wt=wv>>1): o in [64ob+32wo, +32), t = 256tc + 128wt + r + 8n.
// launch_bounds(256,3): ~170-reg budget -> no scratch spills (the R3-R5 killer).
__global__ __launch_bounds__(256, 3) void shapeconv_main(const float* __restrict__ x,
                                                         const unsigned short* __restrict__ wswz,
                                                         const float* __restrict__ wn,
                                                         float* __restrict__ partial) {
    __shared__ __align__(16) unsigned short w_lds[64 * 192];   // 24576 B, swizzled
    __shared__ __align__(16) unsigned short x_lds[3 * 320];
    __shared__ float sq_lds[320];
    __shared__ float P_lds[40];
    __shared__ float win_lds[272];     // padded idx t + (t>>4)
    __shared__ float wn_lds[64];
    __shared__ float mred[64];

    const int tc = blockIdx.x;
    const int ob = blockIdx.y;
    const int b  = blockIdx.z;
    const int tid = threadIdx.x;
    const int wv = tid >> 6;
    const int lane = tid & 63;
    const int wo = wv & 1, wt = wv >> 1;
    const int n  = lane & 15;
    const int qp = lane >> 4;
    const int T0 = tc * 256;

    // W stage: async global->LDS, width 16. Linear layout matches the required
    // wave-uniform-base + lane*16 LDS pattern exactly (chunk idx = wv*64+lane+256i).
    {
        const char* src = (const char*)(wswz + ob * 1536 * 8) + tid * 16;
        #pragma unroll
        for (int i = 0; i < 6; ++i) {
            __builtin_amdgcn_global_load_lds(
                (const __attribute__((address_space(1))) unsigned int*)(src + i * 4096),
                (__attribute__((address_space(3))) unsigned int*)((char*)w_lds + wv * 1024 + i * 4096),
                16, 0, 0);
        }
    }
    if (tid < 64) wn_lds[tid] = wn[ob * 64 + tid];

    // x tile -> bf16 LDS (coalesced float4)
    if (tid < 240) {
        int c = tid / 80, j4 = tid - c * 80;
        int l = T0 + j4 * 4;
        float4 v = make_float4(0.f, 0.f, 0.f, 0.f);
        if (l < LL) v = *(const float4*)(x + (b * 3 + c) * LL + l);
        uint2 pk;
        pk.x = f2bf(v.x) | (f2bf(v.y) << 16);
        pk.y = f2bf(v.z) | (f2bf(v.w) << 16);
        *(uint2*)(x_lds + c * 320 + j4 * 4) = pk;
    }
    // sq[j] fp32 (L1-hot re-read of same lines)
    for (int j = tid; j < 320; j += 256) {
        int l = T0 + j;
        float s = 0.f;
        if (l < LL) {
            #pragma unroll
            for (int c = 0; c < 3; ++c) {
                float v = x[(b * 3 + c) * LL + l];
                s = fmaf(v, v, s);
            }
        }
        sq_lds[j] = s;
    }
    // P8 partials
    if (tid < 40) {
        float s = 0.f;
        #pragma unroll
        for (int k = 0; k < 8; ++k) {
            int l = T0 + tid * 8 + k;
            if (l < LL) {
                #pragma unroll
                for (int c = 0; c < 3; ++c) {
                    float v = x[(b * 3 + c) * LL + l];
                    s = fmaf(v, v, s);
                }
            }
        }
        P_lds[tid] = s;
    }
    __syncthreads();   // B1 (drains global_load_lds vmcnt too)

    // win[t] = 0.5 * sum_{k<64} sq[t+k]; invalid t -> +1e30
    {
        int a = tid >> 3, bb2 = tid & 7;
        float s = 0.f;
        #pragma unroll
        for (int i = 1; i <= 7; ++i) s += P_lds[a + i];
        #pragma unroll
        for (int k = 0; k < 8; ++k)
            s += (k >= bb2) ? sq_lds[8 * a + k] : sq_lds[8 * a + 64 + k];
        int pi = tid + (tid >> 4);
        win_lds[pi] = (T0 + tid < WW) ? 0.5f * s : 1e30f;
    }
    __syncthreads();   // B2

    // acc init with -(wn + win)
    f32x4 acc[2][8];
    {
        float wl[8];
        #pragma unroll
        for (int r = 0; r < 8; ++r) {
            int tl = 128 * wt + r + 8 * n;
            wl[r] = win_lds[tl + (tl >> 4)];
        }
        #pragma unroll
        for (int ot = 0; ot < 2; ++ot)
            #pragma unroll
            for (int rg = 0; rg < 4; ++rg) {
                float nw = wn_lds[32 * wo + 16 * ot + 4 * qp + rg];
                #pragma unroll
                for (int r = 0; r < 8; ++r)
                    acc[ot][r][rg] = -nw - wl[r];
            }
    }

    // K-loop: 6 ks x 8 r x 2 ot = 96 MFMAs/wave
    const char* xb = (const char*)x_lds;
    #pragma unroll
    for (int ks = 0; ks < 6; ++ks) {
        int c = ks >> 1, h = ks & 1;
        int e0b = c * 640 + 256 * wt + 64 * h + 16 * (n + qp);
        AB2 D;
        D.p.a = *(const int4*)(xb + e0b);
        D.p.b = *(const int4*)(xb + e0b + 16);
        AB a0, a1;
        const int4* wq = (const int4*)w_lds + (ks * 4 + qp) * 64 + 32 * wo;
        a0.i4 = wq[n];
        a1.i4 = wq[16 + n];
        #pragma unroll
        for (int r = 0; r < 8; ++r) {
            AB bf;
            int s = r >> 1;
            if ((r & 1) == 0) {
                bf.i[0] = D.i[s]; bf.i[1] = D.i[s + 1]; bf.i[2] = D.i[s + 2]; bf.i[3] = D.i[s + 3];
            } else {
                #pragma unroll
                for (int d = 0; d < 4; ++d)
                    bf.i[d] = (int)(((unsigned)D.i[s + d] >> 16) | ((unsigned)D.i[s + d + 1] << 16));
            }
            acc[0][r] = __builtin_amdgcn_mfma_f32_16x16x32_bf16(a0.v, bf.v, acc[0][r], 0, 0, 0);
            acc[1][r] = __builtin_amdgcn_mfma_f32_16x16x32_bf16(a1.v, bf.v, acc[1][r], 0, 0, 0);
        }
    }

    // epilogue: register max -> cross-lane over n -> wt-pair combine -> dump
    float m2[2][4];
    #pragma unroll
    for (int ot = 0; ot < 2; ++ot)
        #pragma unroll
        for (int rg = 0; rg < 4; ++rg) {
            float mm = acc[ot][0][rg];
            #pragma unroll
            for (int r = 1; r < 8; ++r) mm = fmaxf(mm, acc[ot][r][rg]);
            m2[ot][rg] = mm;
        }
    #pragma unroll
    for (int s = 1; s <= 8; s <<= 1)
        #pragma unroll
        for (int ot = 0; ot < 2; ++ot)
            #pragma unroll
            for (int rg = 0; rg < 4; ++rg)
                m2[ot][rg] = fmaxf(m2[ot][rg], __shfl_xor(m2[ot][rg], s, 64));

    if (wt == 1 && n == 0) {
        #pragma unroll
        for (int ot = 0; ot < 2; ++ot)
            #pragma unroll
            for (int rg = 0; rg < 4; ++rg)
                mred[32 * wo + 16 * ot + 4 * qp + rg] = m2[ot][rg];
    }
    __syncthreads();   // B3
    if (wt == 0 && n == 0) {
        #pragma unroll
        for (int ot = 0; ot < 2; ++ot)
            #pragma unroll
            for (int rg = 0; rg < 4; ++rg) {
                int oi = 32 * wo + 16 * ot + 4 * qp + rg;
                float v = fmaxf(m2[ot][rg], mred[oi]);
                partial[((size_t)(b * TC + tc) * 2 + ob) * 64 + oi] = v;
            }
    }
}

// max over the 32 t-chunks, scale by -2
__global__ __launch_bounds__(256) void reduce_kernel(const float* __restrict__ partial,
                                                     float* __restrict__ out) {
    int idx = blockIdx.x * 256 + threadIdx.x;   // 4096 = 32*128
    int b = idx >> 7, o = idx & 127;
    const float* pp = partial + ((size_t)b * TC * 2 + (o >> 6)) * 64 + (o & 63);
    float mx = -FLT_MAX;
    #pragma unroll 8
    for (int tcc = 0; tcc < TC; ++tcc) mx = fmaxf(mx, pp[(size_t)tcc * 128]);
    out[idx] = -2.f * mx;
}

extern "C" void kernel_launch(void* const* d_in, const int* in_sizes, int n_in,
                              void* d_out, int out_size, void* d_ws, size_t ws_size,
                              hipStream_t stream) {
    const float* x = (const float*)d_in[0];   // [32][3][8192]
    const float* w = (const float*)d_in[1];   // [128][3][64]
    float* out = (float*)d_out;               // [32][128]

    // ws: wswz bf16 swizzled [3072 x 16B] (49152 B) | wn f32 [128] | partial f32 [32][32][2][64]
    unsigned short* wswz = (unsigned short*)d_ws;
    float* wn = (float*)((char*)d_ws + 49152);
    float* partial = (float*)((char*)d_ws + 49664);

    prep_kernel<<<13, 256, 0, stream>>>(w, wswz, wn);
    dim3 grid(TC, 2, BB);                     // 2048 blocks
    shapeconv_main<<<grid, 256, 0, stream>>>(x, wswz, wn, partial);
    reduce_kernel<<<16, 256, 0, stream>>>(partial, out);
}

// Round 7
// 74.447 us; speedup vs baseline: 1.1260x; 1.1100x over previous
//
#include <hip/hip_runtime.h>
#include <float.h>

// x: [B=32][C=3][L=8192] f32, weight: [O=128][C=3][K=64] f32
// out[b][o] = -2 * max_t ( conv(b,o,t) - ||w_o||^2/2 - ||win_{b,t}||^2/2 ), t in [0, 8129)
#define BB 32
#define LL 8192
#define OO 128
#define KK 64
#define WW (LL - KK + 1)   // 8129
#define NCH 4              // t-chunks of 256 per block
#define GX 8               // blockIdx.x count: 8*4*256 = 8192 t covered

typedef __attribute__((ext_vector_type(8))) short short8;
typedef __attribute__((ext_vector_type(4))) float f32x4;

union AB { int4 i4; int i[4]; short8 v; };

static __device__ __forceinline__ unsigned int f2bf(float f) {
    unsigned int u = __builtin_bit_cast(unsigned int, f);
    return (u + 0x7FFFu + ((u >> 16) & 1u)) >> 16;   // RNE
}

// ---- prep: W -> bf16 swizzled into A-fragment order; wn[o] = ||w_o||^2/2 ----
// wswz 16B-chunk index (per ob half of 1536): ((ks*4+qp)*64 + o_local); chunk =
// w[o][c*64 + h*32 + qp*8 .. +8) bf16, ks = 2c+h.
__global__ __launch_bounds__(256) void prep_kernel(const float* __restrict__ w,
                                                   unsigned short* __restrict__ wswz,
                                                   float* __restrict__ wn) {
    int g = blockIdx.x * 256 + threadIdx.x;
    if (g < 3072) {
        int ob = (g >= 1536) ? 1 : 0;
        int gg = g - ob * 1536;
        int ksqp = gg >> 6;
        int o2   = gg & 63;
        int ks = ksqp >> 2, qp = ksqp & 3;
        int c = ks >> 1, h = ks & 1;
        const float4* p = (const float4*)(w + (ob * 64 + o2) * 192 + c * 64 + h * 32 + qp * 8);
        float4 v0 = p[0], v1 = p[1];
        int4 pk;
        pk.x = (int)(f2bf(v0.x) | (f2bf(v0.y) << 16));
        pk.y = (int)(f2bf(v0.z) | (f2bf(v0.w) << 16));
        pk.z = (int)(f2bf(v1.x) | (f2bf(v1.y) << 16));
        pk.w = (int)(f2bf(v1.z) | (f2bf(v1.w) << 16));
        ((int4*)wswz)[g] = pk;
    }
    int oo = g - 3072;
    if (oo >= 0 && oo < OO) {
        const float* p = w + oo * 192;
        float s = 0.f;
        for (int i = 0; i < 192; ++i) { float v = p[i]; s = fmaf(v, v, s); }
        wn[oo] = 0.5f * s;
    }
}

// Stage chunk ci into buffer bf: x bf16 tile + sq (fp32) + P8 partials (via shfl).
static __device__ __forceinline__ void stage_chunk(const float* __restrict__ x, int b, int T0,
                                                   unsigned short* xl, float* sql, float* Pl,
                                                   int tid) {
    // x tile: 240 lanes x 16B coalesced, pack to bf16
    if (tid < 240) {
        int c = tid / 80, j4 = tid - c * 80;
        int l = T0 + j4 * 4;
        float4 v = make_float4(0.f, 0.f, 0.f, 0.f);
        if (l < LL) v = *(const float4*)(x + (b * 3 + c) * LL + l);
        uint2 pk;
        pk.x = f2bf(v.x) | (f2bf(v.y) << 16);
        pk.y = f2bf(v.z) | (f2bf(v.w) << 16);
        *(uint2*)(xl + c * 320 + j4 * 4) = pk;
    }
    // sq[j] fp32 + 8-group partials P[a] via in-wave butterfly (no extra barrier)
    {
        int l = T0 + tid;
        float s = 0.f;
        if (l < LL) {
            #pragma unroll
            for (int c = 0; c < 3; ++c) {
                float v = x[(b * 3 + c) * LL + l];
                s = fmaf(v, v, s);
            }
        }
        sql[tid] = s;
        float s8 = s + __shfl_xor(s, 1, 64);
        s8 += __shfl_xor(s8, 2, 64);
        s8 += __shfl_xor(s8, 4, 64);
        if ((tid & 7) == 0) Pl[tid >> 3] = s8;
    }
    if (tid < 64) {
        int j = 256 + tid, l = T0 + j;
        float s = 0.f;
        if (l < LL) {
            #pragma unroll
            for (int c = 0; c < 3; ++c) {
                float v = x[(b * 3 + c) * LL + l];
                s = fmaf(v, v, s);
            }
        }
        sql[j] = s;
        float s8 = s + __shfl_xor(s, 1, 64);
        s8 += __shfl_xor(s8, 2, 64);
        s8 += __shfl_xor(s8, 4, 64);
        if ((tid & 7) == 0) Pl[32 + (tid >> 3)] = s8;
    }
}

// ---- main: grid (8 tcx, 2 ob, 32 b) = 512 blocks, 4 waves, 4 chunks/block ----
// Wave (wo=wv&1, wt=wv>>1): o in [64ob+32wo, +32), t = T0 + 128wt + r + 8n.
// Double-buffered staging: stage(i+1) issues before K-loop(i) -> latency hidden.
__global__ __launch_bounds__(256, 2) void shapeconv_main(const float* __restrict__ x,
                                                         const unsigned short* __restrict__ wswz,
                                                         const float* __restrict__ wn,
                                                         float* __restrict__ partial) {
    __shared__ __align__(16) unsigned short w_lds[64 * 192];     // 24576 B swizzled
    __shared__ __align__(16) unsigned short x_lds[2][3 * 320];   // 2x1920 B
    __shared__ __align__(16) float sq_lds[2][320];
    __shared__ float P_lds[2][40];
    __shared__ float win_lds[272];     // padded idx t + (t>>4)
    __shared__ float wn_lds[64];
    __shared__ float mred[64];

    const int tcx = blockIdx.x;
    const int ob = blockIdx.y;
    const int b  = blockIdx.z;
    const int tid = threadIdx.x;
    const int wv = tid >> 6;
    const int lane = tid & 63;
    const int wo = wv & 1, wt = wv >> 1;
    const int n  = lane & 15;
    const int qp = lane >> 4;
    const int Tb = tcx * (NCH * 256);

    // W stage once per block: async global->LDS width 16, linear layout
    {
        const char* src = (const char*)(wswz + ob * 1536 * 8) + tid * 16;
        #pragma unroll
        for (int i = 0; i < 6; ++i) {
            __builtin_amdgcn_global_load_lds(
                (const __attribute__((address_space(1))) unsigned int*)(src + i * 4096),
                (__attribute__((address_space(3))) unsigned int*)((char*)w_lds + wv * 1024 + i * 4096),
                16, 0, 0);
        }
    }
    if (tid < 64) wn_lds[tid] = wn[ob * 64 + tid];

    stage_chunk(x, b, Tb, x_lds[0], sq_lds[0], P_lds[0], tid);

    float m2[2][4];
    #pragma unroll
    for (int ot = 0; ot < 2; ++ot)
        #pragma unroll
        for (int rg = 0; rg < 4; ++rg) m2[ot][rg] = -FLT_MAX;

    for (int ci = 0; ci < NCH; ++ci) {
        const int bsel = ci & 1;
        const int T0 = Tb + ci * 256;
        __syncthreads();   // B1: staging(ci) + (ci==0: W DMA) visible

        // win[t] = 0.5 * sum_{k<64} sq[t+k]; invalid t -> +1e30
        {
            int a = tid >> 3, bb2 = tid & 7;
            const float* sql = sq_lds[bsel];
            const float* Pl = P_lds[bsel];
            float s = 0.f;
            #pragma unroll
            for (int i = 1; i <= 7; ++i) s += Pl[a + i];
            #pragma unroll
            for (int k = 0; k < 8; ++k)
                s += (k >= bb2) ? sql[8 * a + k] : sql[8 * a + 64 + k];
            int pi = tid + (tid >> 4);
            win_lds[pi] = (T0 + tid < WW) ? 0.5f * s : 1e30f;
        }
        __syncthreads();   // B2: win visible

        // acc init with -(wn + win)
        f32x4 acc[2][8];
        {
            float wl[8];
            #pragma unroll
            for (int r = 0; r < 8; ++r) {
                int tl = 128 * wt + r + 8 * n;
                wl[r] = win_lds[tl + (tl >> 4)];
            }
            #pragma unroll
            for (int ot = 0; ot < 2; ++ot)
                #pragma unroll
                for (int rg = 0; rg < 4; ++rg) {
                    float nw = wn_lds[32 * wo + 16 * ot + 4 * qp + rg];
                    #pragma unroll
                    for (int r = 0; r < 8; ++r)
                        acc[ot][r][rg] = -nw - wl[r];
                }
        }

        // issue next chunk's staging BEFORE the K-loop: its global loads retire
        // behind ~1900 cyc of MFMA; writes target the other buffer (WAR-safe).
        if (ci + 1 < NCH)
            stage_chunk(x, b, T0 + 256, x_lds[1 - bsel], sq_lds[1 - bsel], P_lds[1 - bsel], tid);

        // K-loop: 6 ks x 8 r x 2 ot = 96 MFMAs/wave
        const char* xb = (const char*)x_lds[bsel];
        #pragma unroll
        for (int ks = 0; ks < 6; ++ks) {
            int c = ks >> 1, h = ks & 1;
            int e0b = c * 640 + 256 * wt + 64 * h + 16 * (n + qp);
            int4 Ea = *(const int4*)(xb + e0b);
            int4 Eb = *(const int4*)(xb + e0b + 16);
            int D[8] = {Ea.x, Ea.y, Ea.z, Ea.w, Eb.x, Eb.y, Eb.z, Eb.w};
            AB a0, a1;
            const int4* wq = (const int4*)w_lds + (ks * 4 + qp) * 64 + 32 * wo;
            a0.i4 = wq[n];
            a1.i4 = wq[16 + n];
            #pragma unroll
            for (int r = 0; r < 8; ++r) {
                AB bf;
                int s = r >> 1;
                if ((r & 1) == 0) {
                    bf.i[0] = D[s]; bf.i[1] = D[s + 1]; bf.i[2] = D[s + 2]; bf.i[3] = D[s + 3];
                } else {
                    #pragma unroll
                    for (int d = 0; d < 4; ++d)
                        bf.i[d] = (int)(((unsigned)D[s + d] >> 16) | ((unsigned)D[s + d + 1] << 16));
                }
                acc[0][r] = __builtin_amdgcn_mfma_f32_16x16x32_bf16(a0.v, bf.v, acc[0][r], 0, 0, 0);
                acc[1][r] = __builtin_amdgcn_mfma_f32_16x16x32_bf16(a1.v, bf.v, acc[1][r], 0, 0, 0);
            }
        }

        // per-chunk register max
        #pragma unroll
        for (int ot = 0; ot < 2; ++ot)
            #pragma unroll
            for (int rg = 0; rg < 4; ++rg) {
                float mm = m2[ot][rg];
                #pragma unroll
                for (int r = 0; r < 8; ++r) mm = fmaxf(mm, acc[ot][r][rg]);
                m2[ot][rg] = mm;
            }
    }

    // cross-lane max over n -> wt-pair combine -> dump
    #pragma unroll
    for (int s = 1; s <= 8; s <<= 1)
        #pragma unroll
        for (int ot = 0; ot < 2; ++ot)
            #pragma unroll
            for (int rg = 0; rg < 4; ++rg)
                m2[ot][rg] = fmaxf(m2[ot][rg], __shfl_xor(m2[ot][rg], s, 64));

    if (wt == 1 && n == 0) {
        #pragma unroll
        for (int ot = 0; ot < 2; ++ot)
            #pragma unroll
            for (int rg = 0; rg < 4; ++rg)
                mred[32 * wo + 16 * ot + 4 * qp + rg] = m2[ot][rg];
    }
    __syncthreads();
    if (wt == 0 && n == 0) {
        #pragma unroll
        for (int ot = 0; ot < 2; ++ot)
            #pragma unroll
            for (int rg = 0; rg < 4; ++rg) {
                int oi = 32 * wo + 16 * ot + 4 * qp + rg;
                float v = fmaxf(m2[ot][rg], mred[oi]);
                partial[((size_t)(b * GX + tcx) * 2 + ob) * 64 + oi] = v;
            }
    }
}

// max over the 8 tcx chunks, scale by -2
__global__ __launch_bounds__(256) void reduce_kernel(const float* __restrict__ partial,
                                                     float* __restrict__ out) {
    int idx = blockIdx.x * 256 + threadIdx.x;   // 4096 = 32*128
    int b = idx >> 7, o = idx & 127;
    const float* pp = partial + ((size_t)b * GX * 2 + (o >> 6)) * 64 + (o & 63);
    float mx = -FLT_MAX;
    #pragma unroll
    for (int t = 0; t < GX; ++t) mx = fmaxf(mx, pp[(size_t)t * 128]);
    out[idx] = -2.f * mx;
}

extern "C" void kernel_launch(void* const* d_in, const int* in_sizes, int n_in,
                              void* d_out, int out_size, void* d_ws, size_t ws_size,
                              hipStream_t stream) {
    const float* x = (const float*)d_in[0];   // [32][3][8192]
    const float* w = (const float*)d_in[1];   // [128][3][64]
    float* out = (float*)d_out;               // [32][128]

    // ws: wswz bf16 swizzled [3072 x 16B] (49152 B) | wn f32 [128] | partial f32 [32][8][2][64]
    unsigned short* wswz = (unsigned short*)d_ws;
    float* wn = (float*)((char*)d_ws + 49152);
    float* partial = (float*)((char*)d_ws + 49664);

    prep_kernel<<<13, 256, 0, stream>>>(w, wswz, wn);
    dim3 grid(GX, 2, BB);                     // 512 blocks, 4 chunks each
    shapeconv_main<<<grid, 256, 0, stream>>>(x, wswz, wn, partial);
    reduce_kernel<<<16, 256, 0, stream>>>(partial, out);
}